// Round 1
// baseline (10637.488 us; speedup 1.0000x reference)
//
#include <hip/hip_runtime.h>

typedef __bf16 bf16;
typedef __attribute__((ext_vector_type(8))) __bf16 bf16x8;
typedef __attribute__((ext_vector_type(4))) float f32x4;

#define B_TOT 16384
#define SEQ 50
#define DH 512
#define ZW 2048  // 4*DH

#define MFMA16(a, b, c) __builtin_amdgcn_mfma_f32_16x16x32_bf16(a, b, c, 0, 0, 0)

__device__ __forceinline__ float fsigm(float x) {
    return __fdividef(1.0f, 1.0f + __expf(-x));
}
// NaN-free tanh: 1 - 2/(e^{2x}+1); safe for large |x|
__device__ __forceinline__ float ftanh(float x) {
    float e = __expf(2.0f * x);
    return 1.0f - __fdividef(2.0f, e + 1.0f);
}

__device__ __forceinline__ void gload16(const bf16* g, void* l) {
    __builtin_amdgcn_global_load_lds(
        (const __attribute__((address_space(1))) unsigned int*)g,
        (__attribute__((address_space(3))) unsigned int*)l, 16, 0, 0);
}

// ---------------------------------------------------------------------------
// Setup kernels
// ---------------------------------------------------------------------------

__global__ void init_state(const float* __restrict__ sh, const float* __restrict__ sc,
                           bf16* __restrict__ h0m, bf16* __restrict__ h0y,
                           float* __restrict__ cm, float* __restrict__ cy) {
    size_t i = (size_t)blockIdx.x * 256 + threadIdx.x;
    float v = sh[i];
    bf16 hb = (bf16)v;
    h0m[i] = hb;
    h0y[i] = hb;
    float c = sc[i];
    cm[i] = c;
    cy[i] = c;
}

// Column reorder: col' = jb*64 + gate*16 + jj  <->  orig col = gate*512 + jb*16 + jj
__device__ __forceinline__ int orig_col(int colp) {
    return ((colp >> 4) & 3) * 512 + ((colp >> 6) << 4) + (colp & 15);
}

// Build transposed+gate-reordered bf16 copies of U_m, U_y, W_m[:512], W_y[:512]
__global__ void reorder_weights(const float* __restrict__ Um, const float* __restrict__ Uy,
                                const float* __restrict__ Wm, const float* __restrict__ Wy,
                                bf16* __restrict__ UtM, bf16* __restrict__ UtY,
                                bf16* __restrict__ WtM, bf16* __restrict__ WtY) {
    int idx = blockIdx.x * 256 + threadIdx.x;
    int which = idx >> 20;  // 2048*512 = 1<<20 per matrix
    int r = idx & ((1 << 20) - 1);
    int colp = r >> 9, k = r & 511;
    int orig = orig_col(colp);
    const float* src = which == 0 ? Um : which == 1 ? Uy : which == 2 ? Wm : Wy;
    bf16* dst = which == 0 ? UtM : which == 1 ? UtY : which == 2 ? WtM : WtY;
    dst[(size_t)colp * 512 + k] = (bf16)src[(size_t)k * ZW + orig];
}

// cond weights (rows D..D+2 of W), gate-reordered, kept f32: Wc[3][2048]
__global__ void reorder_wc(const float* __restrict__ Wm, const float* __restrict__ Wy,
                           float* __restrict__ WcM, float* __restrict__ WcY) {
    int idx = blockIdx.x * 256 + threadIdx.x;
    if (idx >= 2 * 3 * ZW) return;
    int which = idx / (3 * ZW);
    int rr = idx % (3 * ZW);
    int rrow = rr / ZW, colp = rr % ZW;
    int orig = orig_col(colp);
    const float* src = which ? Wy : Wm;
    float* dst = which ? WcY : WcM;
    dst[rrow * ZW + colp] = src[(size_t)(512 + rrow) * ZW + orig];
}

// Head weights transposed (bf16, padded) + per-step ts-constants (prefix sums + bias)
__global__ void build_heads(const float* __restrict__ Whm, const float* __restrict__ bhm,
                            const float* __restrict__ Why, const float* __restrict__ bhy,
                            bf16* __restrict__ WhmT, bf16* __restrict__ WhyT,
                            float* __restrict__ tscm, float* __restrict__ tscy) {
    int i = blockIdx.x * 256 + threadIdx.x;
    const int N1 = 32 * 512, N2 = 16 * 512, N3 = SEQ * 32, N4 = SEQ * 16;
    if (i < N1) {
        int n = i >> 9, k = i & 511;
        WhmT[i] = (bf16)(n < 30 ? Whm[k * 30 + n] : 0.f);
    } else if (i < N1 + N2) {
        int j = i - N1;
        int n = j >> 9, k = j & 511;
        WhyT[j] = (bf16)(n < 15 ? Why[k * 15 + n] : 0.f);
    } else if (i < N1 + N2 + N3) {
        int j = i - (N1 + N2);
        int tt = j >> 5, col = j & 31;
        float v = 0.f;
        if (col < 30) {
            v = bhm[col];
            for (int s = 0; s <= tt; ++s) v += Whm[(512 + s) * 30 + col];
        }
        tscm[j] = v;
    } else if (i < N1 + N2 + N3 + N4) {
        int j = i - (N1 + N2 + N3);
        int tt = j >> 4, col = j & 15;
        float v = 0.f;
        if (col < 15) {
            v = bhy[col];
            for (int s = 0; s <= tt; ++s) v += Why[(512 + s) * 15 + col];
        }
        tscy[j] = v;
    }
}

// ---------------------------------------------------------------------------
// Main GEMM: 128x128 tile, BK=32, global_load_lds staging, 4 waves (2x2).
// MODE 0: xw precompute (z = h0 @ Wt + bias -> bf16 out, gate-reordered cols)
// MODE 1: LSTM step (z = h @ Ut + xw + cond@Wc; gate combine; write h,c)
// blockIdx.z selects merger (0) / yielder (1).
// ---------------------------------------------------------------------------
template <int MODE>
__global__ __launch_bounds__(256) void gemm_step(
    const bf16* __restrict__ Am, const bf16* __restrict__ Ay,
    const bf16* __restrict__ BtM, const bf16* __restrict__ BtY,
    const bf16* __restrict__ xwM, const bf16* __restrict__ xwY,
    const float* __restrict__ WcM, const float* __restrict__ WcY,
    const float* __restrict__ biasM, const float* __restrict__ biasY,
    float* __restrict__ cM, float* __restrict__ cY,
    bf16* __restrict__ hoM, bf16* __restrict__ hoY,
    bf16* __restrict__ xoM, bf16* __restrict__ xoY,
    const float* __restrict__ cond, int t) {
    __shared__ bf16 As[128 * 32];
    __shared__ bf16 Bs[128 * 32];
    __shared__ float WcS[384];

    const int tid = threadIdx.x;
    const int wave = tid >> 6, lane = tid & 63;
    const int bx = blockIdx.x, by = blockIdx.y, bz = blockIdx.z;
    const int brow = bx * 128, ncb = by * 128;

    const bf16* A = bz ? Ay : Am;
    const bf16* Bt = bz ? BtY : BtM;

    if (MODE == 1) {
        const float* Wc = bz ? WcY : WcM;
        for (int i = tid; i < 384; i += 256)
            WcS[i] = Wc[(i >> 7) * ZW + ncb + (i & 127)];
    }

    f32x4 acc[4][4];
#pragma unroll
    for (int m = 0; m < 4; ++m)
#pragma unroll
        for (int n = 0; n < 4; ++n) acc[m][n] = (f32x4){0.f, 0.f, 0.f, 0.f};

    const int srow = tid >> 2;       // 0..63
    const int sk = (tid & 3) << 3;   // 0,8,16,24
    const bf16* Ab = A + (size_t)(brow + srow) * DH + sk;
    const bf16* Bb = Bt + (size_t)(ncb + srow) * DH + sk;
    char* AsW = (char*)As + wave * 1024;
    char* BsW = (char*)Bs + wave * 1024;

    const int fr = lane & 15, fq = lane >> 4;
    const int wr = wave >> 1, wc = wave & 1;

    for (int k0 = 0; k0 < DH; k0 += 32) {
        gload16(Ab + k0, AsW);
        gload16(Ab + k0 + 64 * DH, AsW + 4096);
        gload16(Bb + k0, BsW);
        gload16(Bb + k0 + 64 * DH, BsW + 4096);
        __syncthreads();
        bf16x8 af[4], bg[4];
#pragma unroll
        for (int m = 0; m < 4; ++m)
            af[m] = *(const bf16x8*)&As[(wr * 64 + m * 16 + fr) * 32 + fq * 8];
#pragma unroll
        for (int n = 0; n < 4; ++n)
            bg[n] = *(const bf16x8*)&Bs[(wc * 64 + n * 16 + fr) * 32 + fq * 8];
#pragma unroll
        for (int m = 0; m < 4; ++m)
#pragma unroll
            for (int n = 0; n < 4; ++n)
                acc[m][n] = MFMA16(af[m], bg[n], acc[m][n]);
        __syncthreads();
    }

    if (MODE == 0) {
        const float* bias = bz ? biasY : biasM;
        bf16* XO = bz ? xoY : xoM;
#pragma unroll
        for (int m = 0; m < 4; ++m)
#pragma unroll
            for (int j = 0; j < 4; ++j) {
                const int row = brow + wr * 64 + m * 16 + fq * 4 + j;
#pragma unroll
                for (int n = 0; n < 4; ++n) {
                    int colp = ncb + wc * 64 + n * 16 + fr;
                    XO[(size_t)row * ZW + colp] = (bf16)(acc[m][n][j] + bias[orig_col(colp)]);
                }
            }
    } else {
        float* Cb = bz ? cY : cM;
        bf16* Ho = bz ? hoY : hoM;
        const bf16* xw = bz ? xwY : xwM;
        const int hcol = (by * 2 + wc) * 16 + fr;
#pragma unroll
        for (int m = 0; m < 4; ++m)
#pragma unroll
            for (int j = 0; j < 4; ++j) {
                const int row = brow + wr * 64 + m * 16 + fq * 4 + j;
                const float* cnd = cond + ((size_t)row * SEQ + t) * 3;
                float c0 = cnd[0], c1 = cnd[1], c2 = cnd[2];
                float z[4];
#pragma unroll
                for (int g = 0; g < 4; ++g) {
                    int cc = wc * 64 + g * 16 + fr;
                    float zv = acc[m][g][j];
                    zv += (float)xw[(size_t)row * ZW + ncb + cc];
                    zv += c0 * WcS[cc] + c1 * WcS[128 + cc] + c2 * WcS[256 + cc];
                    z[g] = zv;
                }
                float ii = fsigm(z[0]);
                float ff = fsigm(z[1]);
                float gg = ftanh(z[2]);
                float oo = fsigm(z[3]);
                size_t ci = (size_t)row * DH + hcol;
                float cn = ff * Cb[ci] + ii * gg;
                Cb[ci] = cn;
                Ho[ci] = (bf16)(oo * ftanh(cn));
            }
    }
}

// ---------------------------------------------------------------------------
// Heads: per wave 32 rows; z = h @ WhT + tsc; softmax/exp/tanh transforms.
// ---------------------------------------------------------------------------
__global__ __launch_bounds__(256) void heads_step(
    const bf16* __restrict__ hm, const bf16* __restrict__ hy,
    const bf16* __restrict__ WhmT, const bf16* __restrict__ WhyT,
    const float* __restrict__ tscm, const float* __restrict__ tscy,
    float* __restrict__ out, int t) {
    __shared__ float zbuf[4 * 1536];
    const int tid = threadIdx.x, wave = tid >> 6, lane = tid & 63;
    const int fr = lane & 15, fq = lane >> 4;
    const int rbase = blockIdx.x * 128 + wave * 32;

    f32x4 am[2][2], ay[2];
#pragma unroll
    for (int mi = 0; mi < 2; ++mi) {
        am[mi][0] = (f32x4){0.f, 0.f, 0.f, 0.f};
        am[mi][1] = (f32x4){0.f, 0.f, 0.f, 0.f};
        ay[mi] = (f32x4){0.f, 0.f, 0.f, 0.f};
    }

    for (int k0 = 0; k0 < DH; k0 += 32) {
        const size_t ao = (size_t)(rbase + fr) * DH + k0 + fq * 8;
        bf16x8 a0 = *(const bf16x8*)(hm + ao);
        bf16x8 a1 = *(const bf16x8*)(hm + ao + 16 * DH);
        bf16x8 y0 = *(const bf16x8*)(hy + ao);
        bf16x8 y1 = *(const bf16x8*)(hy + ao + 16 * DH);
        const size_t bo = (size_t)fr * DH + k0 + fq * 8;
        bf16x8 b0 = *(const bf16x8*)(WhmT + bo);
        bf16x8 b1 = *(const bf16x8*)(WhmT + bo + 16 * DH);
        bf16x8 yb = *(const bf16x8*)(WhyT + bo);
        am[0][0] = MFMA16(a0, b0, am[0][0]);
        am[0][1] = MFMA16(a0, b1, am[0][1]);
        am[1][0] = MFMA16(a1, b0, am[1][0]);
        am[1][1] = MFMA16(a1, b1, am[1][1]);
        ay[0] = MFMA16(y0, yb, ay[0]);
        ay[1] = MFMA16(y1, yb, ay[1]);
    }

    float* zm = zbuf + wave * 1536;  // [32][32]
    float* zy = zm + 1024;           // [32][16]
#pragma unroll
    for (int mi = 0; mi < 2; ++mi)
#pragma unroll
        for (int j = 0; j < 4; ++j) {
            int rl = mi * 16 + fq * 4 + j;
            zm[rl * 32 + fr] = am[mi][0][j] + tscm[t * 32 + fr];
            zm[rl * 32 + 16 + fr] = am[mi][1][j] + tscm[t * 32 + 16 + fr];
            zy[rl * 16 + fr] = ay[mi][j] + tscy[t * 16 + fr];
        }
    __syncthreads();

    const int r = lane >> 1;
    const size_t grow = (size_t)rbase + r;
    if (!(lane & 1)) {
        float z[30];
#pragma unroll
        for (int i = 0; i < 30; ++i) z[i] = zm[r * 32 + i];
        float* o = out + (grow * SEQ + t) * 30;
        float mx = z[0];
#pragma unroll
        for (int i = 1; i < 5; ++i) mx = fmaxf(mx, z[i]);
        float e[5], s = 0.f;
#pragma unroll
        for (int i = 0; i < 5; ++i) {
            e[i] = __expf(z[i] - mx);
            s += e[i];
        }
        float inv = __fdividef(1.f, s);
#pragma unroll
        for (int i = 0; i < 5; ++i) o[i] = e[i] * inv;
#pragma unroll
        for (int i = 5; i < 10; ++i) o[i] = z[i];
#pragma unroll
        for (int i = 10; i < 15; ++i) o[i] = __expf(z[i]);
#pragma unroll
        for (int i = 15; i < 20; ++i) o[i] = z[i];
#pragma unroll
        for (int i = 20; i < 25; ++i) o[i] = __expf(z[i]);
#pragma unroll
        for (int i = 25; i < 30; ++i) o[i] = ftanh(z[i]);
    } else {
        float z[15];
#pragma unroll
        for (int i = 0; i < 15; ++i) z[i] = zy[r * 16 + i];
        float* o = out + (size_t)B_TOT * SEQ * 30 + (grow * SEQ + t) * 15;
        float mx = z[0];
#pragma unroll
        for (int i = 1; i < 5; ++i) mx = fmaxf(mx, z[i]);
        float e[5], s = 0.f;
#pragma unroll
        for (int i = 0; i < 5; ++i) {
            e[i] = __expf(z[i] - mx);
            s += e[i];
        }
        float inv = __fdividef(1.f, s);
#pragma unroll
        for (int i = 0; i < 5; ++i) o[i] = e[i] * inv;
#pragma unroll
        for (int i = 5; i < 10; ++i) o[i] = z[i];
#pragma unroll
        for (int i = 10; i < 15; ++i) o[i] = __expf(z[i]);
    }
}

// ---------------------------------------------------------------------------
extern "C" void kernel_launch(void* const* d_in, const int* in_sizes, int n_in,
                              void* d_out, int out_size, void* d_ws, size_t ws_size,
                              hipStream_t stream) {
    const float* cond = (const float*)d_in[0];
    const float* sh = (const float*)d_in[1];
    const float* sc = (const float*)d_in[2];
    const float* Wm = (const float*)d_in[3];
    const float* Um = (const float*)d_in[4];
    const float* bm = (const float*)d_in[5];
    const float* Whm = (const float*)d_in[6];
    const float* bhm = (const float*)d_in[7];
    const float* Wy = (const float*)d_in[8];
    const float* Uy = (const float*)d_in[9];
    const float* by_ = (const float*)d_in[10];
    const float* Why = (const float*)d_in[11];
    const float* bhy = (const float*)d_in[12];
    float* out = (float*)d_out;

    char* p = (char*)d_ws;
    auto take = [&](size_t bytes) {
        char* r = p;
        p += (bytes + 255) & ~(size_t)255;
        return r;
    };
    bf16* UtM = (bf16*)take((size_t)ZW * DH * 2);
    bf16* UtY = (bf16*)take((size_t)ZW * DH * 2);
    bf16* WtM = (bf16*)take((size_t)ZW * DH * 2);
    bf16* WtY = (bf16*)take((size_t)ZW * DH * 2);
    float* WcM = (float*)take(3 * ZW * 4);
    float* WcY = (float*)take(3 * ZW * 4);
    bf16* WhmT = (bf16*)take(32 * DH * 2);
    bf16* WhyT = (bf16*)take(16 * DH * 2);
    float* tscm = (float*)take(SEQ * 32 * 4);
    float* tscy = (float*)take(SEQ * 16 * 4);
    bf16* xwM = (bf16*)take((size_t)B_TOT * ZW * 2);
    bf16* xwY = (bf16*)take((size_t)B_TOT * ZW * 2);
    bf16* hM0 = (bf16*)take((size_t)B_TOT * DH * 2);
    bf16* hM1 = (bf16*)take((size_t)B_TOT * DH * 2);
    bf16* hY0 = (bf16*)take((size_t)B_TOT * DH * 2);
    bf16* hY1 = (bf16*)take((size_t)B_TOT * DH * 2);
    float* cMb = (float*)take((size_t)B_TOT * DH * 4);
    float* cYb = (float*)take((size_t)B_TOT * DH * 4);
    bf16* hM[2] = {hM0, hM1};
    bf16* hY[2] = {hY0, hY1};

    init_state<<<(B_TOT * DH) / 256, 256, 0, stream>>>(sh, sc, hM0, hY0, cMb, cYb);
    reorder_weights<<<(4 * ZW * DH) / 256, 256, 0, stream>>>(Um, Uy, Wm, Wy, UtM, UtY, WtM, WtY);
    reorder_wc<<<(2 * 3 * ZW + 255) / 256, 256, 0, stream>>>(Wm, Wy, WcM, WcY);
    build_heads<<<(32 * 512 + 16 * 512 + SEQ * 32 + SEQ * 16 + 255) / 256, 256, 0, stream>>>(
        Whm, bhm, Why, bhy, WhmT, WhyT, tscm, tscy);

    dim3 ggrid(B_TOT / 128, ZW / 128, 2);
    // xw = h0 @ W[:D] + b  (gate-reordered columns), bf16
    gemm_step<0><<<ggrid, 256, 0, stream>>>(hM0, hM0, WtM, WtY, nullptr, nullptr,
                                            nullptr, nullptr, bm, by_, nullptr, nullptr,
                                            nullptr, nullptr, xwM, xwY, cond, 0);

    for (int t = 0; t < SEQ; ++t) {
        const int a = t & 1, b = (t + 1) & 1;
        gemm_step<1><<<ggrid, 256, 0, stream>>>(hM[a], hY[a], UtM, UtY, xwM, xwY,
                                                WcM, WcY, nullptr, nullptr, cMb, cYb,
                                                hM[b], hY[b], nullptr, nullptr, cond, t);
        heads_step<<<B_TOT / 128, 256, 0, stream>>>(hM[b], hY[b], WhmT, WhyT, tscm, tscy, out, t);
    }
}

// Round 2
// 8973.857 us; speedup vs baseline: 1.1854x; 1.1854x over previous
//
#include <hip/hip_runtime.h>

typedef __bf16 bf16;
typedef __attribute__((ext_vector_type(8))) __bf16 bf16x8;
typedef __attribute__((ext_vector_type(4))) float f32x4;

#define B_TOT 16384
#define SEQ 50
#define DH 512
#define ZW 2048  // 4*DH
#define NT 8     // K-tiles of 64 (K = 512)

#define MFMA16(a, b, c) __builtin_amdgcn_mfma_f32_16x16x32_bf16(a, b, c, 0, 0, 0)

__device__ __forceinline__ float fsigm(float x) {
    return __fdividef(1.0f, 1.0f + __expf(-x));
}
__device__ __forceinline__ float ftanh(float x) {
    float e = __expf(2.0f * x);
    return 1.0f - __fdividef(2.0f, e + 1.0f);
}

__device__ __forceinline__ void gload16(const bf16* g, void* l) {
    __builtin_amdgcn_global_load_lds(
        (const __attribute__((address_space(1))) unsigned int*)g,
        (__attribute__((address_space(3))) unsigned int*)l, 16, 0, 0);
}

// ---------------------------------------------------------------------------
// Setup kernels (unchanged from round 1)
// ---------------------------------------------------------------------------

__global__ void init_state(const float* __restrict__ sh, const float* __restrict__ sc,
                           bf16* __restrict__ h0m, bf16* __restrict__ h0y,
                           float* __restrict__ cm, float* __restrict__ cy) {
    size_t i = (size_t)blockIdx.x * 256 + threadIdx.x;
    float v = sh[i];
    bf16 hb = (bf16)v;
    h0m[i] = hb;
    h0y[i] = hb;
    float c = sc[i];
    cm[i] = c;
    cy[i] = c;
}

__device__ __forceinline__ int orig_col(int colp) {
    return ((colp >> 4) & 3) * 512 + ((colp >> 6) << 4) + (colp & 15);
}

__global__ void reorder_weights(const float* __restrict__ Um, const float* __restrict__ Uy,
                                const float* __restrict__ Wm, const float* __restrict__ Wy,
                                bf16* __restrict__ UtM, bf16* __restrict__ UtY,
                                bf16* __restrict__ WtM, bf16* __restrict__ WtY) {
    int idx = blockIdx.x * 256 + threadIdx.x;
    int which = idx >> 20;
    int r = idx & ((1 << 20) - 1);
    int colp = r >> 9, k = r & 511;
    int orig = orig_col(colp);
    const float* src = which == 0 ? Um : which == 1 ? Uy : which == 2 ? Wm : Wy;
    bf16* dst = which == 0 ? UtM : which == 1 ? UtY : which == 2 ? WtM : WtY;
    dst[(size_t)colp * 512 + k] = (bf16)src[(size_t)k * ZW + orig];
}

__global__ void reorder_wc(const float* __restrict__ Wm, const float* __restrict__ Wy,
                           float* __restrict__ WcM, float* __restrict__ WcY) {
    int idx = blockIdx.x * 256 + threadIdx.x;
    if (idx >= 2 * 3 * ZW) return;
    int which = idx / (3 * ZW);
    int rr = idx % (3 * ZW);
    int rrow = rr / ZW, colp = rr % ZW;
    int orig = orig_col(colp);
    const float* src = which ? Wy : Wm;
    float* dst = which ? WcY : WcM;
    dst[rrow * ZW + colp] = src[(size_t)(512 + rrow) * ZW + orig];
}

__global__ void build_heads(const float* __restrict__ Whm, const float* __restrict__ bhm,
                            const float* __restrict__ Why, const float* __restrict__ bhy,
                            bf16* __restrict__ WhmT, bf16* __restrict__ WhyT,
                            float* __restrict__ tscm, float* __restrict__ tscy) {
    int i = blockIdx.x * 256 + threadIdx.x;
    const int N1 = 32 * 512, N2 = 16 * 512, N3 = SEQ * 32, N4 = SEQ * 16;
    if (i < N1) {
        int n = i >> 9, k = i & 511;
        WhmT[i] = (bf16)(n < 30 ? Whm[k * 30 + n] : 0.f);
    } else if (i < N1 + N2) {
        int j = i - N1;
        int n = j >> 9, k = j & 511;
        WhyT[j] = (bf16)(n < 15 ? Why[k * 15 + n] : 0.f);
    } else if (i < N1 + N2 + N3) {
        int j = i - (N1 + N2);
        int tt = j >> 5, col = j & 31;
        float v = 0.f;
        if (col < 30) {
            v = bhm[col];
            for (int s = 0; s <= tt; ++s) v += Whm[(512 + s) * 30 + col];
        }
        tscm[j] = v;
    } else if (i < N1 + N2 + N3 + N4) {
        int j = i - (N1 + N2 + N3);
        int tt = j >> 4, col = j & 15;
        float v = 0.f;
        if (col < 15) {
            v = bhy[col];
            for (int s = 0; s <= tt; ++s) v += Why[(512 + s) * 15 + col];
        }
        tscy[j] = v;
    }
}

// ---------------------------------------------------------------------------
// Main GEMM: 256x256 tile, BK=64, 8 waves (2x4), 8-phase schedule with
// counted vmcnt (T3+T4), setprio around MFMA (T5), chunk-XOR LDS swizzle (T2).
// LDS layout: [buf][kh][256 rows][32 cols] bf16; kh-halves are 16KB stage units.
// Stage schedule per K-tile kt: ph1 A(kt+1,k1) / ph2 B(kt+1,k1) /
//                               ph3 A(kt+2,k0) / ph4 B(kt+2,k0); vmcnt(8) @ ph2,ph4.
// MODE 0: xw precompute; MODE 1: LSTM step with fused gate epilogue.
// ---------------------------------------------------------------------------

#define FENCE() asm volatile("" ::: "memory")
#define BARRIER()                        \
    do {                                 \
        FENCE();                         \
        __builtin_amdgcn_s_barrier();    \
        FENCE();                         \
    } while (0)
#define WAIT_LGKM0()                                          \
    do {                                                      \
        asm volatile("s_waitcnt lgkmcnt(0)" ::: "memory");    \
        __builtin_amdgcn_sched_barrier(0);                    \
    } while (0)
#define WAIT_VM8() asm volatile("s_waitcnt vmcnt(8)" ::: "memory")

template <int MODE>
__global__ __launch_bounds__(512, 2) void gemm_step(
    const bf16* __restrict__ Am, const bf16* __restrict__ Ay,
    const bf16* __restrict__ BtM, const bf16* __restrict__ BtY,
    const bf16* __restrict__ xwM, const bf16* __restrict__ xwY,
    const float* __restrict__ WcM, const float* __restrict__ WcY,
    const float* __restrict__ biasM, const float* __restrict__ biasY,
    float* __restrict__ cM, float* __restrict__ cY,
    bf16* __restrict__ hoM, bf16* __restrict__ hoY,
    bf16* __restrict__ xoM, bf16* __restrict__ xoY,
    const float* __restrict__ cond, int t) {
    __shared__ bf16 As[2][2][256][32];  // 64 KiB
    __shared__ bf16 Bs[2][2][256][32];  // 64 KiB
    __shared__ float WcS[768];

    const int tid = threadIdx.x;
    const int wave = tid >> 6, lane = tid & 63;
    const int brow = blockIdx.x * 256, ncb = blockIdx.y * 256;
    const int bz = blockIdx.z;

    const bf16* A = bz ? Ay : Am;
    const bf16* Bt = bz ? BtY : BtM;

    if (MODE == 1) {
        const float* Wc = bz ? WcY : WcM;
        for (int i = tid; i < 768; i += 512)
            WcS[i] = Wc[(i >> 8) * ZW + ncb + (i & 255)];
    }

    const int fr = lane & 15, fq = lane >> 4;
    const int wr = wave >> 2, wc = wave & 3;

    // ---- staging addresses (inverse-swizzled global source, linear LDS dest)
    const int srow = tid >> 2;                                   // 0..127 (row within half)
    const int sc8 = (((tid & 3) ^ ((srow >> 1) & 3)) << 3);      // element offset of chunk
    const bf16* Asrc = A + (size_t)(brow + srow) * DH + sc8;
    const bf16* Bsrc = Bt + (size_t)(ncb + srow) * DH + sc8;
    char* AsStage = (char*)As + wave * 1024;
    char* BsStage = (char*)Bs + wave * 1024;

    // ---- read addresses (swizzled chunk)
    const int cxor = ((fq ^ ((fr >> 1) & 3)) << 4);  // byte offset of 16B chunk in 64B row
    const char* Ard = (char*)As + (wr * 128 + fr) * 64 + cxor;
    const char* Brd = (char*)Bs + (wc * 64 + fr) * 64 + cxor;

    f32x4 acc[8][4];
#pragma unroll
    for (int m = 0; m < 8; ++m)
#pragma unroll
        for (int n = 0; n < 4; ++n) acc[m][n] = (f32x4){0.f, 0.f, 0.f, 0.f};

    bf16x8 af[4], bg[4];

#define STAGE_A(pb, kh, kts)                                      \
    do {                                                          \
        const bf16* _s = Asrc + (kts) * 64 + (kh) * 32;           \
        char* _d = AsStage + (pb) * 32768 + (kh) * 16384;         \
        gload16(_s, _d);                                          \
        gload16(_s + 128 * DH, _d + 8192);                        \
    } while (0)
#define STAGE_B(pb, kh, kts)                                      \
    do {                                                          \
        const bf16* _s = Bsrc + (kts) * 64 + (kh) * 32;           \
        char* _d = BsStage + (pb) * 32768 + (kh) * 16384;         \
        gload16(_s, _d);                                          \
        gload16(_s + 128 * DH, _d + 8192);                        \
    } while (0)
#define LOAD_AF(pb, kh, mh)                                                    \
    do {                                                                       \
        const char* _a = Ard + (pb) * 32768 + (kh) * 16384 + (mh) * 4096;      \
        af[0] = *(const bf16x8*)(_a);                                          \
        af[1] = *(const bf16x8*)(_a + 1024);                                   \
        af[2] = *(const bf16x8*)(_a + 2048);                                   \
        af[3] = *(const bf16x8*)(_a + 3072);                                   \
    } while (0)
#define LOAD_BG(pb, kh)                                                        \
    do {                                                                       \
        const char* _b = Brd + (pb) * 32768 + (kh) * 16384;                    \
        bg[0] = *(const bf16x8*)(_b);                                          \
        bg[1] = *(const bf16x8*)(_b + 1024);                                   \
        bg[2] = *(const bf16x8*)(_b + 2048);                                   \
        bg[3] = *(const bf16x8*)(_b + 3072);                                   \
    } while (0)
#define MFMA_Q(mh)                                                             \
    do {                                                                       \
        __builtin_amdgcn_s_setprio(1);                                         \
        _Pragma("unroll") for (int _m = 0; _m < 4; ++_m)                       \
            _Pragma("unroll") for (int _n = 0; _n < 4; ++_n)                   \
                acc[(mh) * 4 + _m][_n] =                                       \
                    MFMA16(af[_m], bg[_n], acc[(mh) * 4 + _m][_n]);            \
        __builtin_amdgcn_s_setprio(0);                                         \
        __builtin_amdgcn_sched_barrier(0);                                     \
    } while (0)

    // ---- prologue: stage tile0 (k0,k1) + tile1 (k0); allow 4 units in flight
    STAGE_A(0, 0, 0);
    STAGE_B(0, 0, 0);
    STAGE_A(0, 1, 0);
    STAGE_B(0, 1, 0);
    STAGE_A(1, 0, 1);
    STAGE_B(1, 0, 1);
    WAIT_VM8();
    BARRIER();

    for (int kt = 0; kt < NT; ++kt) {
        const int p = kt & 1, q = p ^ 1;
        const int t1 = (kt + 1 < NT) ? kt + 1 : NT - 1;  // clamped (dummy at tail)
        const int t2 = (kt + 2 < NT) ? kt + 2 : NT - 1;
        // PH1: (k0, mh0) + stage A(kt+1, k1)
        LOAD_AF(p, 0, 0);
        LOAD_BG(p, 0);
        STAGE_A(q, 1, t1);
        BARRIER();
        WAIT_LGKM0();
        MFMA_Q(0);
        BARRIER();
        // PH2: (k0, mh1) + stage B(kt+1, k1) + vmcnt
        LOAD_AF(p, 0, 1);
        STAGE_B(q, 1, t1);
        BARRIER();
        WAIT_LGKM0();
        MFMA_Q(1);
        WAIT_VM8();
        BARRIER();
        // PH3: (k1, mh0) + stage A(kt+2, k0)
        LOAD_AF(p, 1, 0);
        LOAD_BG(p, 1);
        STAGE_A(p, 0, t2);
        BARRIER();
        WAIT_LGKM0();
        MFMA_Q(0);
        BARRIER();
        // PH4: (k1, mh1) + stage B(kt+2, k0) + vmcnt
        LOAD_AF(p, 1, 1);
        STAGE_B(p, 0, t2);
        BARRIER();
        WAIT_LGKM0();
        MFMA_Q(1);
        WAIT_VM8();
        BARRIER();
    }

    // ---- epilogue
    if (MODE == 0) {
        const float* bias = bz ? biasY : biasM;
        bf16* XO = bz ? xoY : xoM;
#pragma unroll
        for (int m = 0; m < 8; ++m)
#pragma unroll
            for (int j = 0; j < 4; ++j) {
                const int row = brow + wr * 128 + m * 16 + fq * 4 + j;
#pragma unroll
                for (int n = 0; n < 4; ++n) {
                    int colp = ncb + wc * 64 + n * 16 + fr;
                    XO[(size_t)row * ZW + colp] = (bf16)(acc[m][n][j] + bias[orig_col(colp)]);
                }
            }
    } else {
        float* Cb = bz ? cY : cM;
        bf16* Ho = bz ? hoY : hoM;
        const bf16* xw = bz ? xwY : xwM;
        const int hcol = (blockIdx.y * 4 + wc) * 16 + fr;
        const int ccbase = wc * 64 + fr;
#pragma unroll
        for (int m = 0; m < 8; ++m)
#pragma unroll
            for (int j = 0; j < 4; ++j) {
                const int row = brow + wr * 128 + m * 16 + fq * 4 + j;
                const float* cnd = cond + ((size_t)row * SEQ + t) * 3;
                float c0 = cnd[0], c1 = cnd[1], c2 = cnd[2];
                const bf16* xwr = xw + (size_t)row * ZW + ncb + ccbase;
                float z[4];
#pragma unroll
                for (int g = 0; g < 4; ++g) {
                    const int cc = ccbase + g * 16;
                    z[g] = acc[m][g][j] + (float)xwr[g * 16] + c0 * WcS[cc] +
                           c1 * WcS[256 + cc] + c2 * WcS[512 + cc];
                }
                float ii = fsigm(z[0]);
                float ff = fsigm(z[1]);
                float gg = ftanh(z[2]);
                float oo = fsigm(z[3]);
                size_t ci = (size_t)row * DH + hcol;
                float cn = ff * Cb[ci] + ii * gg;
                Cb[ci] = cn;
                Ho[ci] = (bf16)(oo * ftanh(cn));
            }
    }
#undef STAGE_A
#undef STAGE_B
#undef LOAD_AF
#undef LOAD_BG
#undef MFMA_Q
}

// ---------------------------------------------------------------------------
// Heads: 2 waves/block, 32 rows per wave; 256 blocks to cover the chip.
// ---------------------------------------------------------------------------
__global__ __launch_bounds__(128) void heads_step(
    const bf16* __restrict__ hm, const bf16* __restrict__ hy,
    const bf16* __restrict__ WhmT, const bf16* __restrict__ WhyT,
    const float* __restrict__ tscm, const float* __restrict__ tscy,
    float* __restrict__ out, int t) {
    __shared__ float zbuf[2 * 1536];
    const int tid = threadIdx.x, wave = tid >> 6, lane = tid & 63;
    const int fr = lane & 15, fq = lane >> 4;
    const int rbase = blockIdx.x * 64 + wave * 32;

    f32x4 am[2][2], ay[2];
#pragma unroll
    for (int mi = 0; mi < 2; ++mi) {
        am[mi][0] = (f32x4){0.f, 0.f, 0.f, 0.f};
        am[mi][1] = (f32x4){0.f, 0.f, 0.f, 0.f};
        ay[mi] = (f32x4){0.f, 0.f, 0.f, 0.f};
    }

    for (int k0 = 0; k0 < DH; k0 += 32) {
        const size_t ao = (size_t)(rbase + fr) * DH + k0 + fq * 8;
        bf16x8 a0 = *(const bf16x8*)(hm + ao);
        bf16x8 a1 = *(const bf16x8*)(hm + ao + 16 * DH);
        bf16x8 y0 = *(const bf16x8*)(hy + ao);
        bf16x8 y1 = *(const bf16x8*)(hy + ao + 16 * DH);
        const size_t bo = (size_t)fr * DH + k0 + fq * 8;
        bf16x8 b0 = *(const bf16x8*)(WhmT + bo);
        bf16x8 b1 = *(const bf16x8*)(WhmT + bo + 16 * DH);
        bf16x8 yb = *(const bf16x8*)(WhyT + bo);
        am[0][0] = MFMA16(a0, b0, am[0][0]);
        am[0][1] = MFMA16(a0, b1, am[0][1]);
        am[1][0] = MFMA16(a1, b0, am[1][0]);
        am[1][1] = MFMA16(a1, b1, am[1][1]);
        ay[0] = MFMA16(y0, yb, ay[0]);
        ay[1] = MFMA16(y1, yb, ay[1]);
    }

    float* zm = zbuf + wave * 1536;  // [32][32]
    float* zy = zm + 1024;           // [32][16]
#pragma unroll
    for (int mi = 0; mi < 2; ++mi)
#pragma unroll
        for (int j = 0; j < 4; ++j) {
            int rl = mi * 16 + fq * 4 + j;
            zm[rl * 32 + fr] = am[mi][0][j] + tscm[t * 32 + fr];
            zm[rl * 32 + 16 + fr] = am[mi][1][j] + tscm[t * 32 + 16 + fr];
            zy[rl * 16 + fr] = ay[mi][j] + tscy[t * 16 + fr];
        }
    __syncthreads();

    const int r = lane >> 1;
    const size_t grow = (size_t)rbase + r;
    if (!(lane & 1)) {
        float z[30];
#pragma unroll
        for (int i = 0; i < 30; ++i) z[i] = zm[r * 32 + i];
        float* o = out + (grow * SEQ + t) * 30;
        float mx = z[0];
#pragma unroll
        for (int i = 1; i < 5; ++i) mx = fmaxf(mx, z[i]);
        float e[5], s = 0.f;
#pragma unroll
        for (int i = 0; i < 5; ++i) {
            e[i] = __expf(z[i] - mx);
            s += e[i];
        }
        float inv = __fdividef(1.f, s);
#pragma unroll
        for (int i = 0; i < 5; ++i) o[i] = e[i] * inv;
#pragma unroll
        for (int i = 5; i < 10; ++i) o[i] = z[i];
#pragma unroll
        for (int i = 10; i < 15; ++i) o[i] = __expf(z[i]);
#pragma unroll
        for (int i = 15; i < 20; ++i) o[i] = z[i];
#pragma unroll
        for (int i = 20; i < 25; ++i) o[i] = __expf(z[i]);
#pragma unroll
        for (int i = 25; i < 30; ++i) o[i] = ftanh(z[i]);
    } else {
        float z[15];
#pragma unroll
        for (int i = 0; i < 15; ++i) z[i] = zy[r * 16 + i];
        float* o = out + (size_t)B_TOT * SEQ * 30 + (grow * SEQ + t) * 15;
        float mx = z[0];
#pragma unroll
        for (int i = 1; i < 5; ++i) mx = fmaxf(mx, z[i]);
        float e[5], s = 0.f;
#pragma unroll
        for (int i = 0; i < 5; ++i) {
            e[i] = __expf(z[i] - mx);
            s += e[i];
        }
        float inv = __fdividef(1.f, s);
#pragma unroll
        for (int i = 0; i < 5; ++i) o[i] = e[i] * inv;
#pragma unroll
        for (int i = 5; i < 10; ++i) o[i] = z[i];
#pragma unroll
        for (int i = 10; i < 15; ++i) o[i] = __expf(z[i]);
    }
}

// ---------------------------------------------------------------------------
extern "C" void kernel_launch(void* const* d_in, const int* in_sizes, int n_in,
                              void* d_out, int out_size, void* d_ws, size_t ws_size,
                              hipStream_t stream) {
    const float* cond = (const float*)d_in[0];
    const float* sh = (const float*)d_in[1];
    const float* sc = (const float*)d_in[2];
    const float* Wm = (const float*)d_in[3];
    const float* Um = (const float*)d_in[4];
    const float* bm = (const float*)d_in[5];
    const float* Whm = (const float*)d_in[6];
    const float* bhm = (const float*)d_in[7];
    const float* Wy = (const float*)d_in[8];
    const float* Uy = (const float*)d_in[9];
    const float* by_ = (const float*)d_in[10];
    const float* Why = (const float*)d_in[11];
    const float* bhy = (const float*)d_in[12];
    float* out = (float*)d_out;

    char* p = (char*)d_ws;
    auto take = [&](size_t bytes) {
        char* r = p;
        p += (bytes + 255) & ~(size_t)255;
        return r;
    };
    bf16* UtM = (bf16*)take((size_t)ZW * DH * 2);
    bf16* UtY = (bf16*)take((size_t)ZW * DH * 2);
    bf16* WtM = (bf16*)take((size_t)ZW * DH * 2);
    bf16* WtY = (bf16*)take((size_t)ZW * DH * 2);
    float* WcM = (float*)take(3 * ZW * 4);
    float* WcY = (float*)take(3 * ZW * 4);
    bf16* WhmT = (bf16*)take(32 * DH * 2);
    bf16* WhyT = (bf16*)take(16 * DH * 2);
    float* tscm = (float*)take(SEQ * 32 * 4);
    float* tscy = (float*)take(SEQ * 16 * 4);
    bf16* xwM = (bf16*)take((size_t)B_TOT * ZW * 2);
    bf16* xwY = (bf16*)take((size_t)B_TOT * ZW * 2);
    bf16* hM0 = (bf16*)take((size_t)B_TOT * DH * 2);
    bf16* hM1 = (bf16*)take((size_t)B_TOT * DH * 2);
    bf16* hY0 = (bf16*)take((size_t)B_TOT * DH * 2);
    bf16* hY1 = (bf16*)take((size_t)B_TOT * DH * 2);
    float* cMb = (float*)take((size_t)B_TOT * DH * 4);
    float* cYb = (float*)take((size_t)B_TOT * DH * 4);
    bf16* hM[2] = {hM0, hM1};
    bf16* hY[2] = {hY0, hY1};

    init_state<<<(B_TOT * DH) / 256, 256, 0, stream>>>(sh, sc, hM0, hY0, cMb, cYb);
    reorder_weights<<<(4 * ZW * DH) / 256, 256, 0, stream>>>(Um, Uy, Wm, Wy, UtM, UtY, WtM, WtY);
    reorder_wc<<<(2 * 3 * ZW + 255) / 256, 256, 0, stream>>>(Wm, Wy, WcM, WcY);
    build_heads<<<(32 * 512 + 16 * 512 + SEQ * 32 + SEQ * 16 + 255) / 256, 256, 0, stream>>>(
        Whm, bhm, Why, bhy, WhmT, WhyT, tscm, tscy);

    dim3 ggrid(B_TOT / 256, ZW / 256, 2);
    gemm_step<0><<<ggrid, 512, 0, stream>>>(hM0, hM0, WtM, WtY, nullptr, nullptr,
                                            nullptr, nullptr, bm, by_, nullptr, nullptr,
                                            nullptr, nullptr, xwM, xwY, cond, 0);

    for (int t = 0; t < SEQ; ++t) {
        const int a = t & 1, b = (t + 1) & 1;
        gemm_step<1><<<ggrid, 512, 0, stream>>>(hM[a], hY[a], UtM, UtY, xwM, xwY,
                                                WcM, WcY, nullptr, nullptr, cMb, cYb,
                                                hM[b], hY[b], nullptr, nullptr, cond, t);
        heads_step<<<B_TOT / 64, 128, 0, stream>>>(hM[b], hY[b], WhmT, WhyT, tscm, tscy, out, t);
    }
}

// Round 3
// 8019.387 us; speedup vs baseline: 1.3265x; 1.1190x over previous
//
#include <hip/hip_runtime.h>

typedef __bf16 bf16;
typedef __attribute__((ext_vector_type(8))) __bf16 bf16x8;
typedef __attribute__((ext_vector_type(4))) __bf16 bf16x4;
typedef __attribute__((ext_vector_type(4))) float f32x4;

#define B_TOT 16384
#define SEQ 50
#define DH 512
#define ZW 2048  // 4*DH
#define NT 8     // K-tiles of 64 (K = 512)

#define MFMA16(a, b, c) __builtin_amdgcn_mfma_f32_16x16x32_bf16(a, b, c, 0, 0, 0)

__device__ __forceinline__ float fsigm(float x) {
    return __fdividef(1.0f, 1.0f + __expf(-x));
}
__device__ __forceinline__ float ftanh(float x) {
    float e = __expf(2.0f * x);
    return 1.0f - __fdividef(2.0f, e + 1.0f);
}

__device__ __forceinline__ void gload16(const bf16* g, void* l) {
    __builtin_amdgcn_global_load_lds(
        (const __attribute__((address_space(1))) unsigned int*)g,
        (__attribute__((address_space(3))) unsigned int*)l, 16, 0, 0);
}

// ---------------------------------------------------------------------------
// Setup kernels
// ---------------------------------------------------------------------------

__global__ void init_state(const float* __restrict__ sh, const float* __restrict__ sc,
                           bf16* __restrict__ h0m, bf16* __restrict__ h0y,
                           float* __restrict__ cm, float* __restrict__ cy) {
    size_t i = (size_t)blockIdx.x * 256 + threadIdx.x;
    float v = sh[i];
    bf16 hb = (bf16)v;
    h0m[i] = hb;
    h0y[i] = hb;
    float c = sc[i];
    cm[i] = c;
    cy[i] = c;
}

// Column reorder: col' = jb*64 + gate*16 + jj  <->  orig col = gate*512 + jb*16 + jj
__device__ __forceinline__ int orig_col(int colp) {
    return ((colp >> 4) & 3) * 512 + ((colp >> 6) << 4) + (colp & 15);
}

__global__ void reorder_weights(const float* __restrict__ Um, const float* __restrict__ Uy,
                                const float* __restrict__ Wm, const float* __restrict__ Wy,
                                bf16* __restrict__ UtM, bf16* __restrict__ UtY,
                                bf16* __restrict__ WtM, bf16* __restrict__ WtY) {
    int idx = blockIdx.x * 256 + threadIdx.x;
    int which = idx >> 20;
    int r = idx & ((1 << 20) - 1);
    int colp = r >> 9, k = r & 511;
    int orig = orig_col(colp);
    const float* src = which == 0 ? Um : which == 1 ? Uy : which == 2 ? Wm : Wy;
    bf16* dst = which == 0 ? UtM : which == 1 ? UtY : which == 2 ? WtM : WtY;
    dst[(size_t)colp * 512 + k] = (bf16)src[(size_t)k * ZW + orig];
}

// Wc2[hcol][r(3)][g(4)] f32  (per z): epilogue reads 3 x b128 per lane
__global__ void build_wc2(const float* __restrict__ Wm, const float* __restrict__ Wy,
                          float* __restrict__ Wc2M, float* __restrict__ Wc2Y) {
    int idx = blockIdx.x * 256 + threadIdx.x;
    if (idx >= 2 * 512 * 12) return;
    int which = idx / 6144;
    int r2 = idx % 6144;
    int hcol = r2 / 12, rg = r2 % 12;
    int r = rg >> 2, g = rg & 3;
    const float* src = which ? Wy : Wm;
    float* dst = which ? Wc2Y : Wc2M;
    dst[hcol * 12 + rg] = src[(size_t)(512 + r) * ZW + g * 512 + hcol];
}

// condT4[t][row][4] f32 (padded) — one b128 per (row,t)
__global__ void cond_transpose(const float* __restrict__ cond, float* __restrict__ condT4) {
    int idx = blockIdx.x * 256 + threadIdx.x;
    if (idx >= SEQ * B_TOT) return;
    int t = idx / B_TOT, row = idx % B_TOT;
    const float* s = cond + ((size_t)row * SEQ + t) * 3;
    f32x4 v = {s[0], s[1], s[2], 0.f};
    *(f32x4*)(condT4 + (size_t)idx * 4) = v;
}

__global__ void build_heads(const float* __restrict__ Whm, const float* __restrict__ bhm,
                            const float* __restrict__ Why, const float* __restrict__ bhy,
                            bf16* __restrict__ WhmT, bf16* __restrict__ WhyT,
                            float* __restrict__ tscm, float* __restrict__ tscy) {
    int i = blockIdx.x * 256 + threadIdx.x;
    const int N1 = 32 * 512, N2 = 16 * 512, N3 = SEQ * 32, N4 = SEQ * 16;
    if (i < N1) {
        int n = i >> 9, k = i & 511;
        WhmT[i] = (bf16)(n < 30 ? Whm[k * 30 + n] : 0.f);
    } else if (i < N1 + N2) {
        int j = i - N1;
        int n = j >> 9, k = j & 511;
        WhyT[j] = (bf16)(n < 15 ? Why[k * 15 + n] : 0.f);
    } else if (i < N1 + N2 + N3) {
        int j = i - (N1 + N2);
        int tt = j >> 5, col = j & 31;
        float v = 0.f;
        if (col < 30) {
            v = bhm[col];
            for (int s = 0; s <= tt; ++s) v += Whm[(512 + s) * 30 + col];
        }
        tscm[j] = v;
    } else if (i < N1 + N2 + N3 + N4) {
        int j = i - (N1 + N2 + N3);
        int tt = j >> 4, col = j & 15;
        float v = 0.f;
        if (col < 15) {
            v = bhy[col];
            for (int s = 0; s <= tt; ++s) v += Why[(512 + s) * 15 + col];
        }
        tscy[j] = v;
    }
}

// ---------------------------------------------------------------------------
// Main GEMM: 128x128 tile, BK=64, 4 waves (2x2), 8-phase-style schedule with
// counted vmcnt(4), setprio, chunk-XOR swizzle. LDS = 64 KiB -> 2 blocks/CU,
// so one block's epilogue overlaps the other's K-loop.
// MODE 0: xw precompute into gathered layout xw2[row][hcol][4 gates] (bf16).
// MODE 1: LSTM step; vectorized epilogue (b64 xw, b128 cond, b128 Wc).
// ---------------------------------------------------------------------------

#define FENCE() asm volatile("" ::: "memory")
#define BARRIER()                        \
    do {                                 \
        FENCE();                         \
        __builtin_amdgcn_s_barrier();    \
        FENCE();                         \
    } while (0)
#define WAIT_LGKM0()                                          \
    do {                                                      \
        asm volatile("s_waitcnt lgkmcnt(0)" ::: "memory");    \
        __builtin_amdgcn_sched_barrier(0);                    \
    } while (0)
#define WAIT_VM4() asm volatile("s_waitcnt vmcnt(4)" ::: "memory")

template <int MODE>
__global__ __launch_bounds__(256, 2) void gemm_step(
    const bf16* __restrict__ Am, const bf16* __restrict__ Ay,
    const bf16* __restrict__ BtM, const bf16* __restrict__ BtY,
    const bf16* __restrict__ xwM, const bf16* __restrict__ xwY,
    const float* __restrict__ Wc2M, const float* __restrict__ Wc2Y,
    const float* __restrict__ biasM, const float* __restrict__ biasY,
    float* __restrict__ cM, float* __restrict__ cY,
    bf16* __restrict__ hoM, bf16* __restrict__ hoY,
    bf16* __restrict__ xoM, bf16* __restrict__ xoY,
    const float* __restrict__ condT4, int t) {
    __shared__ bf16 As[2][2][128][32];  // 32 KiB
    __shared__ bf16 Bs[2][2][128][32];  // 32 KiB

    const int tid = threadIdx.x;
    const int wave = tid >> 6, lane = tid & 63;
    const int brow = blockIdx.x * 128, ncb = blockIdx.y * 128;
    const int bz = blockIdx.z;

    const bf16* A = bz ? Ay : Am;
    const bf16* Bt = bz ? BtY : BtM;

    const int fr = lane & 15, fq = lane >> 4;
    const int wr = wave >> 1, wc = wave & 1;

    // staging: inverse-swizzled global source, linear LDS dest
    const int srow = tid >> 2;                               // 0..63
    const int sc8 = (((tid & 3) ^ ((srow >> 1) & 3)) << 3);  // element offset
    const bf16* Asrc = A + (size_t)(brow + srow) * DH + sc8;
    const bf16* Bsrc = Bt + (size_t)(ncb + srow) * DH + sc8;
    char* AsStage = (char*)As + wave * 1024;
    char* BsStage = (char*)Bs + wave * 1024;

    // reads: swizzled chunk
    const int cxor = ((fq ^ ((fr >> 1) & 3)) << 4);
    const char* Ard = (char*)As + (wr * 64 + fr) * 64 + cxor;
    const char* Brd = (char*)Bs + (wc * 64 + fr) * 64 + cxor;

    f32x4 acc[4][4];
#pragma unroll
    for (int m = 0; m < 4; ++m)
#pragma unroll
        for (int n = 0; n < 4; ++n) acc[m][n] = (f32x4){0.f, 0.f, 0.f, 0.f};

    bf16x8 af[4], bg[4];

#define STAGE_A(pb, kh, kts)                                  \
    do {                                                      \
        const bf16* _s = Asrc + (kts) * 64 + (kh) * 32;       \
        char* _d = AsStage + (pb) * 16384 + (kh) * 8192;      \
        gload16(_s, _d);                                      \
        gload16(_s + 64 * DH, _d + 4096);                     \
    } while (0)
#define STAGE_B(pb, kh, kts)                                  \
    do {                                                      \
        const bf16* _s = Bsrc + (kts) * 64 + (kh) * 32;       \
        char* _d = BsStage + (pb) * 16384 + (kh) * 8192;      \
        gload16(_s, _d);                                      \
        gload16(_s + 64 * DH, _d + 4096);                     \
    } while (0)
#define LOAD_AF(pb, kh)                                                   \
    do {                                                                  \
        const char* _a = Ard + (pb) * 16384 + (kh) * 8192;                \
        af[0] = *(const bf16x8*)(_a);                                     \
        af[1] = *(const bf16x8*)(_a + 1024);                              \
        af[2] = *(const bf16x8*)(_a + 2048);                              \
        af[3] = *(const bf16x8*)(_a + 3072);                              \
    } while (0)
#define LOAD_BG(pb, kh)                                                   \
    do {                                                                  \
        const char* _b = Brd + (pb) * 16384 + (kh) * 8192;                \
        bg[0] = *(const bf16x8*)(_b);                                     \
        bg[1] = *(const bf16x8*)(_b + 1024);                              \
        bg[2] = *(const bf16x8*)(_b + 2048);                              \
        bg[3] = *(const bf16x8*)(_b + 3072);                              \
    } while (0)
#define MFMA_Q()                                                          \
    do {                                                                  \
        __builtin_amdgcn_s_setprio(1);                                    \
        _Pragma("unroll") for (int _m = 0; _m < 4; ++_m)                  \
            _Pragma("unroll") for (int _n = 0; _n < 4; ++_n)              \
                acc[_m][_n] = MFMA16(af[_m], bg[_n], acc[_m][_n]);        \
        __builtin_amdgcn_s_setprio(0);                                    \
        __builtin_amdgcn_sched_barrier(0);                                \
    } while (0)

    // prologue: T0 (kh0,kh1) + T1 (kh0); drain T0, keep T1kh0 in flight
    STAGE_A(0, 0, 0);
    STAGE_B(0, 0, 0);
    STAGE_A(0, 1, 0);
    STAGE_B(0, 1, 0);
    STAGE_A(1, 0, 1);
    STAGE_B(1, 0, 1);
    WAIT_VM4();
    BARRIER();

    for (int kt = 0; kt < NT; ++kt) {
        const int p = kt & 1, q = p ^ 1;
        const int t1 = (kt + 1 < NT) ? kt + 1 : NT - 1;
        const int t2 = (kt + 2 < NT) ? kt + 2 : NT - 1;
        // PH1: read (p,kh0); stage T(t1) kh1 -> buf q
        LOAD_AF(p, 0);
        LOAD_BG(p, 0);
        STAGE_A(q, 1, t1);
        STAGE_B(q, 1, t1);
        BARRIER();
        WAIT_LGKM0();
        MFMA_Q();
        WAIT_VM4();
        BARRIER();
        // PH2: read (p,kh1); stage T(t2) kh0 -> buf p
        LOAD_AF(p, 1);
        LOAD_BG(p, 1);
        STAGE_A(p, 0, t2);
        STAGE_B(p, 0, t2);
        BARRIER();
        WAIT_LGKM0();
        MFMA_Q();
        WAIT_VM4();
        BARRIER();
    }

    const int jb = blockIdx.y * 2 + wc;  // 0..31
    const int hcol = jb * 16 + fr;       // 0..511
    const int rowbase = brow + wr * 64 + fq * 4;

    if (MODE == 0) {
        const float* bias = bz ? biasY : biasM;
        bf16* XO = bz ? xoY : xoM;
#pragma unroll
        for (int m = 0; m < 4; ++m)
#pragma unroll
            for (int j = 0; j < 4; ++j) {
                const int row = rowbase + m * 16 + j;
                bf16x4 v;
#pragma unroll
                for (int n = 0; n < 4; ++n) v[n] = (bf16)(acc[m][n][j] + bias[n * 512 + hcol]);
                *(bf16x4*)(XO + (size_t)row * ZW + hcol * 4) = v;
            }
    } else {
        float* Cb = bz ? cY : cM;
        bf16* Ho = bz ? hoY : hoM;
        const bf16* xw = bz ? xwY : xwM;
        const float* Wc2 = bz ? Wc2Y : Wc2M;
        // prefetch everything (independent of acc)
        f32x4 wcv0 = *(const f32x4*)(Wc2 + hcol * 12);
        f32x4 wcv1 = *(const f32x4*)(Wc2 + hcol * 12 + 4);
        f32x4 wcv2 = *(const f32x4*)(Wc2 + hcol * 12 + 8);
        bf16x4 xwv[4][4];
        float cv[4][4];
#pragma unroll
        for (int m = 0; m < 4; ++m)
#pragma unroll
            for (int j = 0; j < 4; ++j) {
                const int row = rowbase + m * 16 + j;
                xwv[m][j] = *(const bf16x4*)(xw + (size_t)row * ZW + hcol * 4);
                cv[m][j] = Cb[(size_t)row * DH + hcol];
            }
#pragma unroll
        for (int m = 0; m < 4; ++m) {
            f32x4 cd[4];
#pragma unroll
            for (int j = 0; j < 4; ++j)
                cd[j] = *(const f32x4*)(condT4 + ((size_t)t * B_TOT + rowbase + m * 16 + j) * 4);
#pragma unroll
            for (int j = 0; j < 4; ++j) {
                float z[4];
#pragma unroll
                for (int g = 0; g < 4; ++g)
                    z[g] = acc[m][g][j] + (float)xwv[m][j][g] + cd[j][0] * wcv0[g] +
                           cd[j][1] * wcv1[g] + cd[j][2] * wcv2[g];
                float ii = fsigm(z[0]);
                float ff = fsigm(z[1]);
                float gg = ftanh(z[2]);
                float oo = fsigm(z[3]);
                const int row = rowbase + m * 16 + j;
                size_t ci = (size_t)row * DH + hcol;
                float cn = ff * cv[m][j] + ii * gg;
                Cb[ci] = cn;
                Ho[ci] = (bf16)(oo * ftanh(cn));
            }
        }
    }
#undef STAGE_A
#undef STAGE_B
#undef LOAD_AF
#undef LOAD_BG
#undef MFMA_Q
}

// ---------------------------------------------------------------------------
// Heads: 512 blocks x 128 threads; 2 waves/block, 16 rows per wave.
// ---------------------------------------------------------------------------
__global__ __launch_bounds__(128) void heads_step(
    const bf16* __restrict__ hm, const bf16* __restrict__ hy,
    const bf16* __restrict__ WhmT, const bf16* __restrict__ WhyT,
    const float* __restrict__ tscm, const float* __restrict__ tscy,
    float* __restrict__ out, int t) {
    __shared__ float zbuf[2 * 768];
    const int tid = threadIdx.x, wave = tid >> 6, lane = tid & 63;
    const int fr = lane & 15, fq = lane >> 4;
    const int rbase = blockIdx.x * 32 + wave * 16;

    f32x4 am0 = {0.f, 0.f, 0.f, 0.f}, am1 = {0.f, 0.f, 0.f, 0.f}, ay0 = {0.f, 0.f, 0.f, 0.f};

    for (int k0 = 0; k0 < DH; k0 += 32) {
        const size_t ao = (size_t)(rbase + fr) * DH + k0 + fq * 8;
        bf16x8 a0 = *(const bf16x8*)(hm + ao);
        bf16x8 y0 = *(const bf16x8*)(hy + ao);
        const size_t bo = (size_t)fr * DH + k0 + fq * 8;
        bf16x8 b0 = *(const bf16x8*)(WhmT + bo);
        bf16x8 b1 = *(const bf16x8*)(WhmT + bo + 16 * DH);
        bf16x8 yb = *(const bf16x8*)(WhyT + bo);
        am0 = MFMA16(a0, b0, am0);
        am1 = MFMA16(a0, b1, am1);
        ay0 = MFMA16(y0, yb, ay0);
    }

    float* zm = zbuf + wave * 768;  // [16][32]
    float* zy = zm + 512;           // [16][16]
#pragma unroll
    for (int j = 0; j < 4; ++j) {
        int rl = fq * 4 + j;
        zm[rl * 32 + fr] = am0[j] + tscm[t * 32 + fr];
        zm[rl * 32 + 16 + fr] = am1[j] + tscm[t * 32 + 16 + fr];
        zy[rl * 16 + fr] = ay0[j] + tscy[t * 16 + fr];
    }
    __syncthreads();

    const int r = lane & 15;
    const size_t grow = (size_t)rbase + r;
    if (lane < 16) {
        float z[30];
#pragma unroll
        for (int i = 0; i < 30; ++i) z[i] = zm[r * 32 + i];
        float* o = out + (grow * SEQ + t) * 30;
        float mx = z[0];
#pragma unroll
        for (int i = 1; i < 5; ++i) mx = fmaxf(mx, z[i]);
        float e[5], s = 0.f;
#pragma unroll
        for (int i = 0; i < 5; ++i) {
            e[i] = __expf(z[i] - mx);
            s += e[i];
        }
        float inv = __fdividef(1.f, s);
#pragma unroll
        for (int i = 0; i < 5; ++i) o[i] = e[i] * inv;
#pragma unroll
        for (int i = 5; i < 10; ++i) o[i] = z[i];
#pragma unroll
        for (int i = 10; i < 15; ++i) o[i] = __expf(z[i]);
#pragma unroll
        for (int i = 15; i < 20; ++i) o[i] = z[i];
#pragma unroll
        for (int i = 20; i < 25; ++i) o[i] = __expf(z[i]);
#pragma unroll
        for (int i = 25; i < 30; ++i) o[i] = ftanh(z[i]);
    } else if (lane < 32) {
        float z[15];
#pragma unroll
        for (int i = 0; i < 15; ++i) z[i] = zy[r * 16 + i];
        float* o = out + (size_t)B_TOT * SEQ * 30 + (grow * SEQ + t) * 15;
        float mx = z[0];
#pragma unroll
        for (int i = 1; i < 5; ++i) mx = fmaxf(mx, z[i]);
        float e[5], s = 0.f;
#pragma unroll
        for (int i = 0; i < 5; ++i) {
            e[i] = __expf(z[i] - mx);
            s += e[i];
        }
        float inv = __fdividef(1.f, s);
#pragma unroll
        for (int i = 0; i < 5; ++i) o[i] = e[i] * inv;
#pragma unroll
        for (int i = 5; i < 10; ++i) o[i] = z[i];
#pragma unroll
        for (int i = 10; i < 15; ++i) o[i] = __expf(z[i]);
    }
}

// ---------------------------------------------------------------------------
extern "C" void kernel_launch(void* const* d_in, const int* in_sizes, int n_in,
                              void* d_out, int out_size, void* d_ws, size_t ws_size,
                              hipStream_t stream) {
    const float* cond = (const float*)d_in[0];
    const float* sh = (const float*)d_in[1];
    const float* sc = (const float*)d_in[2];
    const float* Wm = (const float*)d_in[3];
    const float* Um = (const float*)d_in[4];
    const float* bm = (const float*)d_in[5];
    const float* Whm = (const float*)d_in[6];
    const float* bhm = (const float*)d_in[7];
    const float* Wy = (const float*)d_in[8];
    const float* Uy = (const float*)d_in[9];
    const float* by_ = (const float*)d_in[10];
    const float* Why = (const float*)d_in[11];
    const float* bhy = (const float*)d_in[12];
    float* out = (float*)d_out;

    char* p = (char*)d_ws;
    auto take = [&](size_t bytes) {
        char* r = p;
        p += (bytes + 255) & ~(size_t)255;
        return r;
    };
    bf16* UtM = (bf16*)take((size_t)ZW * DH * 2);
    bf16* UtY = (bf16*)take((size_t)ZW * DH * 2);
    bf16* WtM = (bf16*)take((size_t)ZW * DH * 2);
    bf16* WtY = (bf16*)take((size_t)ZW * DH * 2);
    float* Wc2M = (float*)take(512 * 12 * 4);
    float* Wc2Y = (float*)take(512 * 12 * 4);
    bf16* WhmT = (bf16*)take(32 * DH * 2);
    bf16* WhyT = (bf16*)take(16 * DH * 2);
    float* tscm = (float*)take(SEQ * 32 * 4);
    float* tscy = (float*)take(SEQ * 16 * 4);
    float* condT4 = (float*)take((size_t)SEQ * B_TOT * 4 * 4);
    bf16* xwM = (bf16*)take((size_t)B_TOT * ZW * 2);
    bf16* xwY = (bf16*)take((size_t)B_TOT * ZW * 2);
    bf16* hM0 = (bf16*)take((size_t)B_TOT * DH * 2);
    bf16* hM1 = (bf16*)take((size_t)B_TOT * DH * 2);
    bf16* hY0 = (bf16*)take((size_t)B_TOT * DH * 2);
    bf16* hY1 = (bf16*)take((size_t)B_TOT * DH * 2);
    float* cMb = (float*)take((size_t)B_TOT * DH * 4);
    float* cYb = (float*)take((size_t)B_TOT * DH * 4);
    bf16* hM[2] = {hM0, hM1};
    bf16* hY[2] = {hY0, hY1};

    init_state<<<(B_TOT * DH) / 256, 256, 0, stream>>>(sh, sc, hM0, hY0, cMb, cYb);
    reorder_weights<<<(4 * ZW * DH) / 256, 256, 0, stream>>>(Um, Uy, Wm, Wy, UtM, UtY, WtM, WtY);
    build_wc2<<<(2 * 512 * 12 + 255) / 256, 256, 0, stream>>>(Wm, Wy, Wc2M, Wc2Y);
    cond_transpose<<<(SEQ * B_TOT + 255) / 256, 256, 0, stream>>>(cond, condT4);
    build_heads<<<(32 * 512 + 16 * 512 + SEQ * 32 + SEQ * 16 + 255) / 256, 256, 0, stream>>>(
        Whm, bhm, Why, bhy, WhmT, WhyT, tscm, tscy);

    dim3 ggrid(B_TOT / 128, ZW / 128, 2);
    gemm_step<0><<<ggrid, 256, 0, stream>>>(hM0, hM0, WtM, WtY, nullptr, nullptr,
                                            nullptr, nullptr, bm, by_, nullptr, nullptr,
                                            nullptr, nullptr, xwM, xwY, condT4, 0);

    for (int t = 0; t < SEQ; ++t) {
        const int a = t & 1, b = (t + 1) & 1;
        gemm_step<1><<<ggrid, 256, 0, stream>>>(hM[a], hY[a], UtM, UtY, xwM, xwY,
                                                Wc2M, Wc2Y, nullptr, nullptr, cMb, cYb,
                                                hM[b], hY[b], nullptr, nullptr, condT4, t);
        heads_step<<<B_TOT / 32, 128, 0, stream>>>(hM[b], hY[b], WhmT, WhyT, tscm, tscy, out, t);
    }
}